// Round 10
// baseline (227.768 us; speedup 1.0000x reference)
//
#include <hip/hip_runtime.h>

typedef unsigned int u32;
typedef unsigned long long u64;

// ---------------- problem constants ----------------
#define NCLS 80
#define NIMG 8
#define PRE_K 1000
#define POST_K 100
#define PBUF_N 2048

__device__ __forceinline__ int HWof(int l){ return l==0?15200:(l==1?3800:950); }
__device__ __forceinline__ float STRof(int l){ return l==0?8.f:(l==1?16.f:32.f); }
__device__ __forceinline__ u32 CAPof(int l){ return l==0?65536u:32768u; }
__device__ __forceinline__ u32 POFFof(int l){ return l==0?0u:(l==1?65536u:98304u); }

struct Ptrs {
  const float* logits[3];
  const float* reg[3];
  const float* ctr[3];
  const float* cofs[3];
  const float* locs[3];
};

// grid split: 149 lvl0-tiles, 38 lvl1, 10 lvl2 (2048 float4 per tile)
#define NB0 149
#define NB1 38
#define NBALL 197

// ---------------- workspace layout (bytes) ----------------
// zeroed every launch:
#define OFF_HIST1 0u            // 24*512*4 = 49152
#define OFF_PCNT  49152u        // 96
#define OFF_THR   49248u        // 24*8*4 = 768 {B1, cntAbove, T22, kk, ok,-,-,-}
#define OFF_MCNT  50016u        // 32
#define OFF_KEEP  50048u        // 8*48*8 = 3072
#define ZERO_BYTES 53120u
// not zeroed:
#define OFF_POOL  53248u        // 8*131072*8 = 8388608
#define OFF_CLS   8441856u      // 8*3072*4 = 98304
#define OFF_MERG  8540160u      // 8*3072*8*4 = 786432  (total ~9.33 MB)

__device__ __forceinline__ float sigmoidf(float x){ return 1.0f/(1.0f+expf(-x)); }

// ---------------- streaming pass body -----------------------------------
// Scores computed with inline sigmoid(ctr) (bit-identical to precomputed path).
// REFILL=false: exact coarse 512-bin hist (bits>>21; score<1 -> bin<512) +
//               push keys with bin >= static floor into pool (LDS staged).
// REFILL=true : push keys with bin >= B1 (exact fallback).
template<int LVL, bool REFILL>
__device__ __forceinline__ void pass_body(int tile, int img, const Ptrs& p,
                                          u32* pcnt, const u32* thr, u64* pool,
                                          u64* pbuf, u32* shctl, u32* lh, u32* hist1){
  constexpr int HW   = LVL==0?15200:(LVL==1?3800:950);
  constexpr int NE   = 80*HW;
  constexpr int NF4  = NE/4;
  const u32 CAP = CAPof(LVL);
  const int pair = img*3 + LVL;
  const size_t poff = (size_t)img*131072u + POFFof(LVL);
  // static floors: score >= {0.3125, 0.25, 0.125}
  const u32 tbin = REFILL ? thr[pair*8+0] : (LVL==0?501u:(LVL==1?500u:496u));
  const float4* plane = (const float4*)(p.logits[LVL] + (size_t)img*NE);
  const float* cptr = p.ctr[LVL] + (size_t)img*HW;
  if (!REFILL){ for (int b=threadIdx.x;b<512;b+=256) lh[b]=0; }
  if (threadIdx.x==0) shctl[0]=0;
  __syncthreads();
  #pragma unroll
  for (int k=0;k<8;++k){
    int f4 = tile*2048 + k*256 + (int)threadIdx.x;
    if (f4 < NF4){
      float4 v = plane[f4];
      int e0 = f4*4;
      int cls0 = e0 / HW;
      int loc0 = e0 - cls0*HW;
      float ss[4];
      if (LVL==2){                        // HW=950 not %4: rows can split a float4
        #pragma unroll
        for (int j=0;j<4;++j){ int e=e0+j; int c=e/HW; ss[j]=sigmoidf(cptr[e-c*HW]); }
      } else {                            // HW%4==0: aligned float4 ctr load
        float4 c4 = *(const float4*)(cptr + loc0);
        ss[0]=sigmoidf(c4.x); ss[1]=sigmoidf(c4.y); ss[2]=sigmoidf(c4.z); ss[3]=sigmoidf(c4.w);
      }
      float vv[4] = {v.x,v.y,v.z,v.w};
      #pragma unroll
      for (int j=0;j<4;++j){
        float sl = sigmoidf(vv[j]);
        if (sl > 0.05f){
          u32 bits = __float_as_uint(sl * ss[j]);
          if (!REFILL) atomicAdd(&lh[bits>>21], 1u);
          if ((bits>>21) >= tbin){
            int e = e0 + j, cls, loc;
            if (LVL==2){ cls=e/HW; loc=e-cls*HW; } else { cls=cls0; loc=loc0+j; }
            u64 key = ((u64)bits<<32) | (u64)(0xFFFFFFFFu - (u32)(loc*NCLS + cls));
            u32 id = atomicAdd(&shctl[0], 1u);
            if (id < (u32)PBUF_N) pbuf[id] = key;
            else { u32 g = atomicAdd(&pcnt[pair],1u); if (g<CAP) pool[poff+g]=key; }
          }
        }
      }
    }
  }
  __syncthreads();
  u32 m = shctl[0]; if (m > (u32)PBUF_N) m = PBUF_N;
  if (threadIdx.x==0 && m) shctl[2] = atomicAdd(&pcnt[pair], m);
  __syncthreads();
  for (u32 i=threadIdx.x; i<m; i+=256){
    u32 d = shctl[2] + i;
    if (d < CAP) pool[poff+d] = pbuf[i];
  }
  if (!REFILL){
    for (int b=threadIdx.x;b<512;b+=256){ u32 c=lh[b]; if (c) atomicAdd(&hist1[pair*512+b], c); }
  }
}

// ---------------- K1: THE single full-data pass (hist + collect) ------------
__global__ __launch_bounds__(256)
void fused_pass(Ptrs p, u32* pcnt, u64* pool, u32* hist1){
  __shared__ u64 pbuf[PBUF_N];
  __shared__ u32 shctl[4];
  __shared__ u32 lh[512];
  const int bx=(int)blockIdx.x, img=(int)blockIdx.y;
  if (bx<NB0)          pass_body<0,false>(bx,        img,p,pcnt,nullptr,pool,pbuf,shctl,lh,hist1);
  else if (bx<NB0+NB1) pass_body<1,false>(bx-NB0,    img,p,pcnt,nullptr,pool,pbuf,shctl,lh,hist1);
  else                 pass_body<2,false>(bx-NB0-NB1,img,p,pcnt,nullptr,pool,pbuf,shctl,lh,hist1);
}

// ---------------- K2: fused coarse+fine select ----------------
// B1/cntAbove always exact (full hist). Fine selection from pool when pool is
// provably complete for bins >= B1 (B1 >= static floor && no overflow).
__global__ __launch_bounds__(256)
void select_kernel(const u32* hist1, u32* pcnt, u32* thr, const u64* pool){
  const int pair=(int)blockIdx.x, lvl=pair%3, img=pair/3;
  __shared__ u32 h[512];
  __shared__ u32 h2[2048];
  __shared__ u32 seg[256], exc[256];
  __shared__ u32 sB1, sCnt, sTot;
  const int t = (int)threadIdx.x;
  u32 b0 = hist1[pair*512 + (511-2*t)];
  u32 b1 = hist1[pair*512 + (511-(2*t+1))];
  h[511-2*t]=b0; h[511-(2*t+1)]=b1;
  seg[t]=b0+b1;
  __syncthreads();
  if (t==0){ u32 run=0; for(int i=0;i<256;++i){ exc[i]=run; run+=seg[i]; } sTot=run; }
  __syncthreads();
  const u32 kk = min(sTot, (u32)PRE_K);
  if (t==0){
    thr[pair*8+3]=kk;
    if (kk==0){ thr[pair*8+2]=0xFFFFFFFFu; thr[pair*8+4]=1u; }
  }
  if (kk==0) return;
  // coarse boundary bin
  u32 cum = exc[t];
  #pragma unroll
  for (int q=0;q<2;++q){
    int bin = 511-(2*t+q); u32 c=h[bin];
    if (c && cum<kk && cum+c>=kk){ sB1=(u32)bin; sCnt=cum; }
    cum+=c;
  }
  __syncthreads();
  const u32 B1=sB1, cntAb=sCnt;
  const u32 tbin = lvl==0?501u:(lvl==1?500u:496u);
  const u32 pc = pcnt[pair];
  const bool ok = (pc <= CAPof(lvl)) && (B1 >= tbin);
  if (t==0){
    thr[pair*8+0]=B1; thr[pair*8+1]=cntAb; thr[pair*8+4]=ok?1u:0u;
    if (!ok) pcnt[pair]=0;                  // refill will repopulate
  }
  if (!ok) return;
  // fine hist from pool (complete for bin >= B1)
  for (int b=t;b<2048;b+=256) h2[b]=0;
  __syncthreads();
  const size_t poff = (size_t)img*131072u + POFFof(lvl);
  for (u32 i=t;i<pc;i+=256){
    u64 key = pool[poff+i];
    if ((u32)(key>>53)==B1) atomicAdd(&h2[(u32)(key>>42)&0x7FFu],1u);
  }
  __syncthreads();
  const u32 KK2 = kk - cntAb;
  u32 part=0;
  #pragma unroll
  for (int q=0;q<8;++q) part += h2[2047-(t*8+q)];
  seg[t]=part;
  __syncthreads();
  if (t==0){ u32 run=0; for(int i=0;i<256;++i){ exc[i]=run; run+=seg[i]; } }
  __syncthreads();
  cum = exc[t];
  #pragma unroll
  for (int q=0;q<8;++q){
    int bin=2047-(t*8+q); u32 c=h2[bin];
    if (c && cum<KK2 && cum+c>=KK2) thr[pair*8+2]=(B1<<11)|(u32)bin;
    cum+=c;
  }
}

// ---------------- fallback: exact refill of pool with bin >= B1 --------------
__global__ __launch_bounds__(256)
void refill_pass(Ptrs p, u32* pcnt, const u32* thr, u64* pool){
  const int bx=(int)blockIdx.x, img=(int)blockIdx.y;
  const int lvl = bx<NB0?0:(bx<NB0+NB1?1:2);
  if (thr[(img*3+lvl)*8+4]) return;             // pool was sufficient
  __shared__ u64 pbuf[PBUF_N];
  __shared__ u32 shctl[4];
  if (lvl==0)      pass_body<0,true>(bx,        img,p,pcnt,thr,pool,pbuf,shctl,nullptr,nullptr);
  else if (lvl==1) pass_body<1,true>(bx-NB0,    img,p,pcnt,thr,pool,pbuf,shctl,nullptr,nullptr);
  else             pass_body<2,true>(bx-NB0-NB1,img,p,pcnt,thr,pool,pbuf,shctl,nullptr,nullptr);
}

// ---------------- fallback: fine select after refill ----------------
__global__ __launch_bounds__(256)
void selB2(u32* thr, const u32* pcnt, const u64* pool){
  const int pair=(int)blockIdx.x, lvl=pair%3, img=pair/3;
  if (thr[pair*8+4]) return;                    // ok path already did fine select
  const u32 kk = thr[pair*8+3];
  const u32 B1 = thr[pair*8+0];
  const u32 KK2 = kk - thr[pair*8+1];
  __shared__ u32 h2[2048], seg[256], exc[256];
  const int t=(int)threadIdx.x;
  for (int b=t;b<2048;b+=256) h2[b]=0;
  __syncthreads();
  const size_t poff = (size_t)img*131072u + POFFof(lvl);
  const u32 pc = min(pcnt[pair], CAPof(lvl));
  for (u32 i=t;i<pc;i+=256){
    u64 key = pool[poff+i];
    if ((u32)(key>>53)==B1) atomicAdd(&h2[(u32)(key>>42)&0x7FFu],1u);
  }
  __syncthreads();
  u32 part=0;
  #pragma unroll
  for (int q=0;q<8;++q) part += h2[2047-(t*8+q)];
  seg[t]=part;
  __syncthreads();
  if (t==0){ u32 run=0; for(int i=0;i<256;++i){ exc[i]=run; run+=seg[i]; } }
  __syncthreads();
  u32 cum = exc[t];
  #pragma unroll
  for (int q=0;q<8;++q){
    int bin=2047-(t*8+q); u32 c=h2[bin];
    if (c && cum<KK2 && cum+c>=KK2) thr[pair*8+2]=(B1<<11)|(u32)bin;
    cum+=c;
  }
}

// ---------------- K3: fused sort+merge+decode (one block per image) ----------
// Composite key (bits<<23)|((2-l)<<21)|(~flat21): descending order == per-level
// sort (bits desc, flat asc) stably merged by (bits desc, concat-idx asc).
// Per-level top-kk caps enforced via packed 3-counter prefix scan.
__global__ __launch_bounds__(1024)
void sortmerge(Ptrs p, const u32* thr, const u32* pcnt, const u64* pool,
               float* merged, float* clsarr, u32* mcnt){
#pragma clang fp contract(off)
  const int img = (int)blockIdx.x;
  const int tid = (int)threadIdx.x;
  __shared__ u64 a[4096];
  __shared__ u64 part[1024];
  __shared__ u32 cnt;
  for (int i=tid;i<4096;i+=1024) a[i]=0ull;
  if (tid==0) cnt=0;
  __syncthreads();
  for (int l=0;l<3;++l){
    const u32 T22 = thr[(img*3+l)*8+2];
    const size_t poff = (size_t)img*131072u + POFFof(l);
    const u32 pc = min(pcnt[img*3+l], CAPof(l));
    for (u32 i=tid;i<pc;i+=1024){
      u64 k = pool[poff+i];
      if ((u32)(k>>42) >= T22){
        u32 id = atomicAdd(&cnt,1u);
        if (id < 4096u){
          u32 bits = (u32)(k>>32);
          u32 flat = ~(u32)k;                        // < 2^21
          a[id] = ((u64)bits<<23) | ((u64)(2-l)<<21) | (u64)(0x1FFFFFu - flat);
        }
      }
    }
  }
  __syncthreads();
  // bitonic sort descending, 4096
  for (int k=2;k<=4096;k<<=1){
    for (int j=k>>1;j>0;j>>=1){
      for (int i=tid;i<4096;i+=1024){
        int ix = i ^ j;
        if (ix > i){
          u64 x=a[i], y=a[ix];
          bool up = ((i & k)==0);
          if (up ? (x<y) : (x>y)){ a[i]=y; a[ix]=x; }
        }
      }
      __syncthreads();
    }
  }
  // per-level exclusive ranks (packed 3x16-bit scan)
  const u32 kkv0=thr[(img*3+0)*8+3], kkv1=thr[(img*3+1)*8+3], kkv2=thr[(img*3+2)*8+3];
  u64 x[4]; int lv[4]; bool val[4]; u64 pref[4];
  u64 inc=0;
  #pragma unroll
  for (int q=0;q<4;++q){
    x[q]=a[4*tid+q]; val[q]=(x[q]!=0ull);
    lv[q]= val[q] ? 2-(int)((x[q]>>21)&3ull) : 0;
    pref[q]=inc;
    if (val[q]) inc += 1ull << (16*lv[q]);
  }
  part[tid]=inc;
  __syncthreads();
  for (int d=1; d<1024; d<<=1){
    u64 y = (tid>=d)? part[tid-d] : 0ull;
    __syncthreads();
    part[tid]+=y;
    __syncthreads();
  }
  u64 base = tid ? part[tid-1] : 0ull;
  __syncthreads();
  bool keep[4]; u32 kpre[4]; u32 kc=0;
  #pragma unroll
  for (int q=0;q<4;++q){
    u32 rank = (u32)(((base + pref[q]) >> (16*lv[q])) & 0xFFFFull);
    u32 kkq = lv[q]==0?kkv0:(lv[q]==1?kkv1:kkv2);
    keep[q] = val[q] && (rank < kkq);
    kpre[q]=kc; kc += keep[q]?1u:0u;
  }
  part[tid]=(u64)kc;
  __syncthreads();
  for (int d=1; d<1024; d<<=1){
    u64 y = (tid>=d)? part[tid-d] : 0ull;
    __syncthreads();
    part[tid]+=y;
    __syncthreads();
  }
  u32 base2 = (u32)(tid ? part[tid-1] : 0ull);
  if (tid==0) mcnt[img] = (u32)part[1023];
  // decode & scatter
  #pragma unroll
  for (int q=0;q<4;++q){
    if (keep[q]){
      u32 pos = base2 + kpre[q];
      u32 bits = (u32)(x[q]>>23);
      int l = lv[q];
      u32 flat = 0x1FFFFFu - (u32)(x[q] & 0x1FFFFFull);
      int loc = (int)(flat / (u32)NCLS);
      int cls = (int)(flat - (u32)loc*NCLS);
      float score = __uint_as_float(bits);
      int HW = HWof(l);
      float lx = p.locs[l][2*loc], ly = p.locs[l][2*loc+1];
      float st = STRof(l);
      const float* rg = p.reg[l] + (size_t)img*4*HW + loc;
      float r0 = rg[0]*st, r1 = rg[HW]*st, r2 = rg[2*(size_t)HW]*st, r3 = rg[3*(size_t)HW]*st;
      float x1 = fminf(fmaxf(lx - r0, 0.f), 1216.f);
      float y1 = fminf(fmaxf(ly - r1, 0.f),  800.f);
      float x2 = fminf(fmaxf(lx + r2, 0.f), 1216.f);
      float y2 = fminf(fmaxf(ly + r3, 0.f),  800.f);
      float* out = merged + (size_t)(img*3072 + pos)*8;
      out[0]=x1; out[1]=y1; out[2]=x2; out[3]=y2;
      out[4]=score; out[5]=(float)cls; out[6]=(float)l; out[7]=(float)loc;
      clsarr[img*3072 + pos] = (float)cls;
    }
  }
}

// ---------------- K4: per-class greedy NMS (640 independent tasks) ----------
__global__ __launch_bounds__(64)
void nms_class(const float* merged_all, const float* clsarr, const u32* mcnt, u64* gkeep){
#pragma clang fp contract(off)
  const int c = (int)blockIdx.x, img = (int)blockIdx.y;
  const float* merged = merged_all + (size_t)img*3072*8;
  const float* carr = clsarr + (size_t)img*3072;
  const int T = (int)mcnt[img];
  const int lane = (int)threadIdx.x;
  __shared__ unsigned short mlist[3072];
  __shared__ float4 kbox[1024];

  float fv[48];
  #pragma unroll
  for (int w=0; w<48; ++w){
    int j = w*64 + lane;
    fv[w] = (j < T) ? carr[j] : -1.0f;
  }
  int base = 0;
  const u64 lanemask = (lane==0) ? 0ull : ((~0ull) >> (64-lane));
  #pragma unroll
  for (int w=0; w<48; ++w){
    bool mem = ((int)fv[w] == c);
    u64 word = __ballot(mem);
    if (mem){
      int rank = base + (int)__popcll(word & lanemask);
      mlist[rank] = (unsigned short)(w*64 + lane);
    }
    base += (int)__popcll(word);
  }
  const int n = base;
  if (n == 0) return;
  __syncthreads();

  const float off = (float)c * 1217.0f;
  int kc = 0;
  for (int t0 = 0; t0 < n; t0 += 64){
    int r = t0 + lane;
    bool valid = (r < n);
    float4 bx = make_float4(0.f,0.f,0.f,0.f);
    int gj = 0;
    if (valid){
      gj = (int)mlist[r];
      const float* rec = merged + (size_t)gj*8;
      bx = make_float4(rec[0]+off, rec[1]+off, rec[2]+off, rec[3]+off);
    }
    float ax = (bx.z-bx.x)*(bx.w-bx.y);
    bool alive_l = valid;
    for (int q=0; q<kc; ++q){
      float4 bq = kbox[q];
      float aq = (bq.z-bq.x)*(bq.w-bq.y);
      float ltx=fmaxf(bq.x,bx.x), lty=fmaxf(bq.y,bx.y);
      float rbx=fminf(bq.z,bx.z), rby=fminf(bq.w,bx.w);
      float wx=fmaxf(rbx-ltx,0.f), wy=fmaxf(rby-lty,0.f);
      float inter=wx*wy;
      float denom=aq+ax; denom=denom-inter; denom=denom+1e-9f;
      if (alive_l && (inter/denom > 0.6f)) alive_l=false;
    }
    u64 alive = __ballot(alive_l);
    while (alive){
      int i = __ffsll((unsigned long long)alive) - 1;
      float bix=__shfl(bx.x,i), biy=__shfl(bx.y,i), biz=__shfl(bx.z,i), biw=__shfl(bx.w,i);
      int gi = __shfl(gj, i);
      if (lane==0){
        atomicOr((unsigned long long*)&gkeep[img*48 + (gi>>6)], 1ull<<(gi&63));
        if (kc < 1024) kbox[kc] = make_float4(bix,biy,biz,biw);
      }
      kc++;
      float ai=(biz-bix)*(biw-biy);
      float ltx=fmaxf(bix,bx.x), lty=fmaxf(biy,bx.y);
      float rbx=fminf(biz,bx.z), rby=fminf(biw,bx.w);
      float wx=fmaxf(rbx-ltx,0.f), wy=fmaxf(rby-lty,0.f);
      float inter=wx*wy;
      float denom=ai+ax; denom=denom-inter; denom=denom+1e-9f;
      bool supp = alive_l && (inter/denom > 0.6f);
      u64 killm = __ballot(supp);
      alive &= ~killm;
      alive &= ~(1ull<<i);
      alive_l = alive_l && !supp;
    }
    __syncthreads();
  }
}

// ---------------- K5: fused emit — one block per (row,img) ----------------
// Each block derives its own kept-index from gkeep (48-word popcount prefix,
// one wave), writes its row's box/score/cls/kv and 128 cofs.
__global__ __launch_bounds__(128)
void emit_kernel(Ptrs p, const float* merged_all, const u64* gkeep, float* out){
  const int r = (int)blockIdx.x, img = (int)blockIdx.y;
  const int tid = (int)threadIdx.x;
  __shared__ int s_i, s_kept;
  if (tid < 64){
    u64 word = (tid < 48) ? gkeep[img*48 + tid] : 0ull;
    int c = (int)__popcll(word);
    int inc = c;
    #pragma unroll
    for (int d=1; d<64; d<<=1){
      int y = __shfl_up(inc, d);
      if (tid >= d) inc += y;
    }
    int excl = inc - c;
    int total = __shfl(inc, 63);
    int kept = total < POST_K ? total : POST_K;
    if (tid==0){ s_kept = kept; s_i = -1; }
    bool sel = (tid<48) && (r < kept) && (excl <= r) && (r < excl + c);
    if (sel){
      u64 w = word; int need = r - excl;
      for (int q=0;q<need;++q) w &= w-1ull;
      s_i = (tid<<6) + (int)__ffsll((unsigned long long)w) - 1;
    }
  }
  __syncthreads();
  const int i = s_i; const int kept = s_kept;
  const bool has = (r < kept) && (i >= 0);
  const float* rec = merged_all + (size_t)img*3072*8 + (size_t)(has?i:0)*8;
  float* obx = out;
  float* osc = out + 3200;
  float* ocl = out + 4000;
  float* ocf = out + 4800;
  float* okv = out + 107200;
  if (tid==0) osc[img*POST_K+r] = has ? sqrtf(fmaxf(rec[4], 1e-12f)) : 0.f;
  if (tid==1) ocl[img*POST_K+r] = has ? rec[5] : -1.0f;
  if (tid==2) okv[img*POST_K+r] = has ? 1.0f : 0.f;
  if (tid>=4 && tid<8) obx[(img*POST_K+r)*4 + (tid-4)] = has ? rec[tid-4] : 0.f;
  float v = 0.f;
  if (has){
    int l = (int)rec[6]; int loc = (int)rec[7];
    int HW = HWof(l);
    v = p.cofs[l][((size_t)img*128 + tid)*HW + loc];
  }
  ocf[(img*POST_K + r)*128 + tid] = v;
}

// ---------------- host ----------------
extern "C" void kernel_launch(void* const* d_in, const int* in_sizes, int n_in,
                              void* d_out, int out_size, void* d_ws, size_t ws_size,
                              hipStream_t stream){
  Ptrs p;
  for (int l=0; l<3; ++l){
    p.locs[l]   = (const float*)d_in[5*l+0];
    p.logits[l] = (const float*)d_in[5*l+1];
    p.reg[l]    = (const float*)d_in[5*l+2];
    p.ctr[l]    = (const float*)d_in[5*l+3];
    p.cofs[l]   = (const float*)d_in[5*l+4];
  }
  char* ws = (char*)d_ws;
  u32* hist1  = (u32*)(ws + OFF_HIST1);
  u32* pcnt   = (u32*)(ws + OFF_PCNT);
  u32* thr    = (u32*)(ws + OFF_THR);
  u32* mcnt   = (u32*)(ws + OFF_MCNT);
  u64* gkeep  = (u64*)(ws + OFF_KEEP);
  u64* pool   = (u64*)(ws + OFF_POOL);
  float* clsarr = (float*)(ws + OFF_CLS);
  float* merged = (float*)(ws + OFF_MERG);

  hipMemsetAsync(ws, 0, ZERO_BYTES, stream);
  fused_pass<<<dim3(NBALL,8), 256, 0, stream>>>(p, pcnt, pool, hist1);
  select_kernel<<<24, 256, 0, stream>>>(hist1, pcnt, thr, pool);
  refill_pass<<<dim3(NBALL,8), 256, 0, stream>>>(p, pcnt, thr, pool);   // no-op when ok
  selB2<<<24, 256, 0, stream>>>(thr, pcnt, pool);                        // no-op when ok
  sortmerge<<<8, 1024, 0, stream>>>(p, thr, pcnt, pool, merged, clsarr, mcnt);
  nms_class<<<dim3(NCLS,8), 64, 0, stream>>>(merged, clsarr, mcnt, gkeep);
  emit_kernel<<<dim3(POST_K,8), 128, 0, stream>>>(p, merged, gkeep, (float*)d_out);
}

// Round 11
// 172.076 us; speedup vs baseline: 1.3236x; 1.3236x over previous
//
#include <hip/hip_runtime.h>

typedef unsigned int u32;
typedef unsigned long long u64;

// ---------------- problem constants ----------------
#define NCLS 80
#define NIMG 8
#define PRE_K 1000
#define POST_K 100
#define PBUF_N 2048

__device__ __forceinline__ int HWof(int l){ return l==0?15200:(l==1?3800:950); }
__device__ __forceinline__ float STRof(int l){ return l==0?8.f:(l==1?16.f:32.f); }
__device__ __forceinline__ u32 CAPof(int l){ return l==0?65536u:32768u; }
__device__ __forceinline__ u32 POFFof(int l){ return l==0?0u:(l==1?65536u:98304u); }

struct Ptrs {
  const float* logits[3];
  const float* reg[3];
  const float* ctr[3];
  const float* cofs[3];
  const float* locs[3];
};

// grid split: 149 lvl0-tiles, 38 lvl1, 10 lvl2 (2048 float4 per tile)
#define NB0 149
#define NB1 38
#define NBALL 197

// ---------------- workspace layout (bytes) ----------------
// zeroed every launch:
#define OFF_HIST1 0u            // 24*512*4 = 49152
#define OFF_PCNT  49152u        // 96
#define OFF_THR   49248u        // 24*8*4 = 768 {B1, cntAbove, T22, kk, ok,-,-,-}
#define OFF_MCNT  50016u        // 32
#define OFF_KEEP  50048u        // 8*48*8 = 3072
#define ZERO_BYTES 53120u
// not zeroed:
#define OFF_POOL  53248u        // 8*131072*8 = 8388608
#define OFF_SORT  8441856u      // 24*1024*8 = 196608
#define OFF_CLS   8638464u      // 8*3072*4 = 98304
#define OFF_MERG  8736768u      // 8*3072*8*4 = 786432  (total ~9.52 MB)

__device__ __forceinline__ float sigmoidf(float x){ return 1.0f/(1.0f+expf(-x)); }

// ---------------- streaming pass body -----------------------------------
// Scores computed with inline sigmoid(ctr) (bit-identical to precomputed path).
// REFILL=false: exact coarse 512-bin hist (bits>>21; score<1 -> bin<512) +
//               push keys with bin >= static floor into pool (LDS staged).
// REFILL=true : push keys with bin >= B1 (exact fallback).
template<int LVL, bool REFILL>
__device__ __forceinline__ void pass_body(int tile, int img, const Ptrs& p,
                                          u32* pcnt, const u32* thr, u64* pool,
                                          u64* pbuf, u32* shctl, u32* lh, u32* hist1){
  constexpr int HW   = LVL==0?15200:(LVL==1?3800:950);
  constexpr int NE   = 80*HW;
  constexpr int NF4  = NE/4;
  const u32 CAP = CAPof(LVL);
  const int pair = img*3 + LVL;
  const size_t poff = (size_t)img*131072u + POFFof(LVL);
  // static floors: score >= {0.3125, 0.25, 0.125}
  const u32 tbin = REFILL ? thr[pair*8+0] : (LVL==0?501u:(LVL==1?500u:496u));
  const float4* plane = (const float4*)(p.logits[LVL] + (size_t)img*NE);
  const float* cptr = p.ctr[LVL] + (size_t)img*HW;
  if (!REFILL){ for (int b=threadIdx.x;b<512;b+=256) lh[b]=0; }
  if (threadIdx.x==0) shctl[0]=0;
  __syncthreads();
  #pragma unroll
  for (int k=0;k<8;++k){
    int f4 = tile*2048 + k*256 + (int)threadIdx.x;
    if (f4 < NF4){
      float4 v = plane[f4];
      int e0 = f4*4;
      int cls0 = e0 / HW;
      int loc0 = e0 - cls0*HW;
      float ss[4];
      if (LVL==2){                        // HW=950 not %4: rows can split a float4
        #pragma unroll
        for (int j=0;j<4;++j){ int e=e0+j; int c=e/HW; ss[j]=sigmoidf(cptr[e-c*HW]); }
      } else {                            // HW%4==0: aligned float4 ctr load
        float4 c4 = *(const float4*)(cptr + loc0);
        ss[0]=sigmoidf(c4.x); ss[1]=sigmoidf(c4.y); ss[2]=sigmoidf(c4.z); ss[3]=sigmoidf(c4.w);
      }
      float vv[4] = {v.x,v.y,v.z,v.w};
      #pragma unroll
      for (int j=0;j<4;++j){
        float sl = sigmoidf(vv[j]);
        if (sl > 0.05f){
          u32 bits = __float_as_uint(sl * ss[j]);
          if (!REFILL) atomicAdd(&lh[bits>>21], 1u);
          if ((bits>>21) >= tbin){
            int e = e0 + j, cls, loc;
            if (LVL==2){ cls=e/HW; loc=e-cls*HW; } else { cls=cls0; loc=loc0+j; }
            u64 key = ((u64)bits<<32) | (u64)(0xFFFFFFFFu - (u32)(loc*NCLS + cls));
            u32 id = atomicAdd(&shctl[0], 1u);
            if (id < (u32)PBUF_N) pbuf[id] = key;
            else { u32 g = atomicAdd(&pcnt[pair],1u); if (g<CAP) pool[poff+g]=key; }
          }
        }
      }
    }
  }
  __syncthreads();
  u32 m = shctl[0]; if (m > (u32)PBUF_N) m = PBUF_N;
  if (threadIdx.x==0 && m) shctl[2] = atomicAdd(&pcnt[pair], m);
  __syncthreads();
  for (u32 i=threadIdx.x; i<m; i+=256){
    u32 d = shctl[2] + i;
    if (d < CAP) pool[poff+d] = pbuf[i];
  }
  if (!REFILL){
    for (int b=threadIdx.x;b<512;b+=256){ u32 c=lh[b]; if (c) atomicAdd(&hist1[pair*512+b], c); }
  }
}

// ---------------- K1: THE single full-data pass (hist + collect) ------------
__global__ __launch_bounds__(256)
void fused_pass(Ptrs p, u32* pcnt, u64* pool, u32* hist1){
  __shared__ u64 pbuf[PBUF_N];
  __shared__ u32 shctl[4];
  __shared__ u32 lh[512];
  const int bx=(int)blockIdx.x, img=(int)blockIdx.y;
  if (bx<NB0)          pass_body<0,false>(bx,        img,p,pcnt,nullptr,pool,pbuf,shctl,lh,hist1);
  else if (bx<NB0+NB1) pass_body<1,false>(bx-NB0,    img,p,pcnt,nullptr,pool,pbuf,shctl,lh,hist1);
  else                 pass_body<2,false>(bx-NB0-NB1,img,p,pcnt,nullptr,pool,pbuf,shctl,lh,hist1);
}

// ---------------- K2: fused coarse+fine select ----------------
// B1/cntAbove always exact (full hist). Fine selection from pool when pool is
// provably complete for bins >= B1 (B1 >= static floor && no overflow).
__global__ __launch_bounds__(256)
void select_kernel(const u32* hist1, u32* pcnt, u32* thr, const u64* pool){
  const int pair=(int)blockIdx.x, lvl=pair%3, img=pair/3;
  __shared__ u32 h[512];
  __shared__ u32 h2[2048];
  __shared__ u32 seg[256], exc[256];
  __shared__ u32 sB1, sCnt, sTot;
  const int t = (int)threadIdx.x;
  u32 b0 = hist1[pair*512 + (511-2*t)];
  u32 b1 = hist1[pair*512 + (511-(2*t+1))];
  h[511-2*t]=b0; h[511-(2*t+1)]=b1;
  seg[t]=b0+b1;
  __syncthreads();
  if (t==0){ u32 run=0; for(int i=0;i<256;++i){ exc[i]=run; run+=seg[i]; } sTot=run; }
  __syncthreads();
  const u32 kk = min(sTot, (u32)PRE_K);
  if (t==0){
    thr[pair*8+3]=kk;
    if (kk==0){ thr[pair*8+2]=0xFFFFFFFFu; thr[pair*8+4]=1u; }
  }
  if (kk==0) return;
  // coarse boundary bin
  u32 cum = exc[t];
  #pragma unroll
  for (int q=0;q<2;++q){
    int bin = 511-(2*t+q); u32 c=h[bin];
    if (c && cum<kk && cum+c>=kk){ sB1=(u32)bin; sCnt=cum; }
    cum+=c;
  }
  __syncthreads();
  const u32 B1=sB1, cntAb=sCnt;
  const u32 tbin = lvl==0?501u:(lvl==1?500u:496u);
  const u32 pc = pcnt[pair];
  const bool ok = (pc <= CAPof(lvl)) && (B1 >= tbin);
  if (t==0){
    thr[pair*8+0]=B1; thr[pair*8+1]=cntAb; thr[pair*8+4]=ok?1u:0u;
    if (!ok) pcnt[pair]=0;                  // refill will repopulate
  }
  if (!ok) return;
  // fine hist from pool (complete for bin >= B1)
  for (int b=t;b<2048;b+=256) h2[b]=0;
  __syncthreads();
  const size_t poff = (size_t)img*131072u + POFFof(lvl);
  for (u32 i=t;i<pc;i+=256){
    u64 key = pool[poff+i];
    if ((u32)(key>>53)==B1) atomicAdd(&h2[(u32)(key>>42)&0x7FFu],1u);
  }
  __syncthreads();
  const u32 KK2 = kk - cntAb;
  u32 part=0;
  #pragma unroll
  for (int q=0;q<8;++q) part += h2[2047-(t*8+q)];
  seg[t]=part;
  __syncthreads();
  if (t==0){ u32 run=0; for(int i=0;i<256;++i){ exc[i]=run; run+=seg[i]; } }
  __syncthreads();
  cum = exc[t];
  #pragma unroll
  for (int q=0;q<8;++q){
    int bin=2047-(t*8+q); u32 c=h2[bin];
    if (c && cum<KK2 && cum+c>=KK2) thr[pair*8+2]=(B1<<11)|(u32)bin;
    cum+=c;
  }
}

// ---------------- fallback: exact refill of pool with bin >= B1 --------------
__global__ __launch_bounds__(256)
void refill_pass(Ptrs p, u32* pcnt, const u32* thr, u64* pool){
  const int bx=(int)blockIdx.x, img=(int)blockIdx.y;
  const int lvl = bx<NB0?0:(bx<NB0+NB1?1:2);
  if (thr[(img*3+lvl)*8+4]) return;             // pool was sufficient
  __shared__ u64 pbuf[PBUF_N];
  __shared__ u32 shctl[4];
  if (lvl==0)      pass_body<0,true>(bx,        img,p,pcnt,thr,pool,pbuf,shctl,nullptr,nullptr);
  else if (lvl==1) pass_body<1,true>(bx-NB0,    img,p,pcnt,thr,pool,pbuf,shctl,nullptr,nullptr);
  else             pass_body<2,true>(bx-NB0-NB1,img,p,pcnt,thr,pool,pbuf,shctl,nullptr,nullptr);
}

// ---------------- K3: per-pair gather+filter, bitonic 2048 sort, top-kk ------
// Prologue computes T22 locally when select took the fallback path (!ok),
// replacing the old selB2 dispatch. 24 blocks — keeps bitonic at 2048/66 stages.
__global__ __launch_bounds__(1024)
void sort_pool(u32* thr, const u32* pcnt, const u64* pool, u64* sorted){
  const int pair=(int)blockIdx.x, lvl=pair%3, img=pair/3;
  __shared__ u64 a[2048];
  __shared__ u32 cnt;
  __shared__ u32 h2[2048], seg[256], exc[256];
  __shared__ u32 sT22;
  const int tid=(int)threadIdx.x;
  const u32 kk = thr[pair*8+3];
  const size_t poff = (size_t)img*131072u + POFFof(lvl);
  const u32 pc = min(pcnt[pair], CAPof(lvl));
  const u32 ok = thr[pair*8+4];
  if (tid==0) sT22 = thr[pair*8+2];
  __syncthreads();
  if (!ok && kk){
    // fine select over refilled pool (all keys have bin >= B1)
    const u32 B1 = thr[pair*8+0];
    const u32 KK2 = kk - thr[pair*8+1];
    for (int b=tid;b<2048;b+=1024) h2[b]=0;
    __syncthreads();
    for (u32 i=tid;i<pc;i+=1024){
      u64 key = pool[poff+i];
      if ((u32)(key>>53)==B1) atomicAdd(&h2[(u32)(key>>42)&0x7FFu],1u);
    }
    __syncthreads();
    if (tid<256){
      u32 part=0;
      #pragma unroll
      for (int q=0;q<8;++q) part += h2[2047-(tid*8+q)];
      seg[tid]=part;
    }
    __syncthreads();
    if (tid==0){ u32 run=0; for(int i=0;i<256;++i){ exc[i]=run; run+=seg[i]; } }
    __syncthreads();
    if (tid<256){
      u32 cum = exc[tid];
      #pragma unroll
      for (int q=0;q<8;++q){
        int bin=2047-(tid*8+q); u32 c=h2[bin];
        if (c && cum<KK2 && cum+c>=KK2) sT22=(B1<<11)|(u32)bin;
        cum+=c;
      }
    }
    __syncthreads();
  }
  const u32 T22 = sT22;
  for (int i=tid;i<2048;i+=1024) a[i]=0ull;
  if (tid==0) cnt=0;
  __syncthreads();
  for (u32 i=tid;i<pc;i+=1024){
    u64 k = pool[poff+i];
    if ((u32)(k>>42) >= T22){
      u32 id = atomicAdd(&cnt,1u);
      if (id < 2048u) a[id]=k;
    }
  }
  __syncthreads();
  const u32 n = min(cnt, 2048u);
  for (int k=2;k<=2048;k<<=1){
    for (int j=k>>1;j>0;j>>=1){
      for (int t=tid;t<2048;t+=1024){
        int ix = t ^ j;
        if (ix > t){
          u64 x=a[t], y=a[ix];
          bool up = ((t & k)==0);
          if (up ? (x<y) : (x>y)){ a[t]=y; a[ix]=x; }
        }
      }
      __syncthreads();
    }
  }
  u32 m = kk < n ? kk : n;
  for (u32 r=tid;r<m;r+=1024) sorted[(size_t)pair*1024+r]=a[r];
  if (tid==0) thr[pair*8+3]=m;
}

// ---------------- K4: 3-way stable merge + box decode (+ class array) --------
__global__ void merge_kernel(Ptrs p, const u32* thr, const u64* sorted,
                             float* merged, float* clsarr, u32* mcnt){
#pragma clang fp contract(off)
  const int img = blockIdx.x;
  __shared__ u64 mk[3][1024];
  __shared__ int n[3];
  if (threadIdx.x < 3) n[threadIdx.x] = (int)thr[(img*3+threadIdx.x)*8+3];
  __syncthreads();
  const int n0=n[0], n1=n[1], n2=n[2];
  for (int idx=threadIdx.x; idx<3*1024; idx+=blockDim.x){
    int l = idx>>10, r = idx&1023;
    if (r < n[l]){
      u64 key = sorted[(size_t)(img*3+l)*1024 + r];
      mk[l][r] = (key & 0xFFFFFFFF00000000ull) |
                 (u64)(0xFFFFFFFFu - (u32)(l*PRE_K + r));  // concat-idx tie-break
    }
  }
  __syncthreads();
  const int T = n0+n1+n2;
  if (threadIdx.x==0) mcnt[img] = (u32)T;
  for (int t=threadIdx.x; t<T; t+=blockDim.x){
    int l, r;
    if (t < n0){ l=0; r=t; }
    else if (t < n0+n1){ l=1; r=t-n0; }
    else { l=2; r=t-n0-n1; }
    u64 x = mk[l][r];
    int pos = r;
    #pragma unroll
    for (int o=0;o<3;++o) if (o!=l){
      int lo=0, hi=n[o];
      while (lo<hi){ int m=(lo+hi)>>1; if (mk[o][m] > x) lo=m+1; else hi=m; }
      pos += lo;
    }
    u64 key = sorted[(size_t)(img*3+l)*1024 + r];
    u32 flat = 0xFFFFFFFFu - (u32)(key & 0xFFFFFFFFull);
    float score = __uint_as_float((u32)(key>>32));
    int HW = HWof(l);
    int loc = (int)(flat / (u32)NCLS);
    int cls = (int)(flat - (u32)loc*NCLS);
    float lx = p.locs[l][2*loc], ly = p.locs[l][2*loc+1];
    float st = STRof(l);
    const float* rg = p.reg[l] + (size_t)img*4*HW + loc;
    float r0 = rg[0]*st, r1 = rg[HW]*st, r2 = rg[2*(size_t)HW]*st, r3 = rg[3*(size_t)HW]*st;
    float x1 = fminf(fmaxf(lx - r0, 0.f), 1216.f);
    float y1 = fminf(fmaxf(ly - r1, 0.f),  800.f);
    float x2 = fminf(fmaxf(lx + r2, 0.f), 1216.f);
    float y2 = fminf(fmaxf(ly + r3, 0.f),  800.f);
    float* out = merged + (size_t)(img*3072 + pos)*8;
    out[0]=x1; out[1]=y1; out[2]=x2; out[3]=y2;
    out[4]=score; out[5]=(float)cls; out[6]=(float)l; out[7]=(float)loc;
    clsarr[img*3072 + pos] = (float)cls;
  }
}

// ---------------- K5: per-class greedy NMS (640 independent tasks) ----------
__global__ __launch_bounds__(64)
void nms_class(const float* merged_all, const float* clsarr, const u32* mcnt, u64* gkeep){
#pragma clang fp contract(off)
  const int c = (int)blockIdx.x, img = (int)blockIdx.y;
  const float* merged = merged_all + (size_t)img*3072*8;
  const float* carr = clsarr + (size_t)img*3072;
  const int T = (int)mcnt[img];
  const int lane = (int)threadIdx.x;
  __shared__ unsigned short mlist[3072];
  __shared__ float4 kbox[1024];

  float fv[48];
  #pragma unroll
  for (int w=0; w<48; ++w){
    int j = w*64 + lane;
    fv[w] = (j < T) ? carr[j] : -1.0f;
  }
  int base = 0;
  const u64 lanemask = (lane==0) ? 0ull : ((~0ull) >> (64-lane));
  #pragma unroll
  for (int w=0; w<48; ++w){
    bool mem = ((int)fv[w] == c);
    u64 word = __ballot(mem);
    if (mem){
      int rank = base + (int)__popcll(word & lanemask);
      mlist[rank] = (unsigned short)(w*64 + lane);
    }
    base += (int)__popcll(word);
  }
  const int n = base;
  if (n == 0) return;
  __syncthreads();

  const float off = (float)c * 1217.0f;
  int kc = 0;
  for (int t0 = 0; t0 < n; t0 += 64){
    int r = t0 + lane;
    bool valid = (r < n);
    float4 bx = make_float4(0.f,0.f,0.f,0.f);
    int gj = 0;
    if (valid){
      gj = (int)mlist[r];
      const float* rec = merged + (size_t)gj*8;
      bx = make_float4(rec[0]+off, rec[1]+off, rec[2]+off, rec[3]+off);
    }
    float ax = (bx.z-bx.x)*(bx.w-bx.y);
    bool alive_l = valid;
    for (int q=0; q<kc; ++q){
      float4 bq = kbox[q];
      float aq = (bq.z-bq.x)*(bq.w-bq.y);
      float ltx=fmaxf(bq.x,bx.x), lty=fmaxf(bq.y,bx.y);
      float rbx=fminf(bq.z,bx.z), rby=fminf(bq.w,bx.w);
      float wx=fmaxf(rbx-ltx,0.f), wy=fmaxf(rby-lty,0.f);
      float inter=wx*wy;
      float denom=aq+ax; denom=denom-inter; denom=denom+1e-9f;
      if (alive_l && (inter/denom > 0.6f)) alive_l=false;
    }
    u64 alive = __ballot(alive_l);
    while (alive){
      int i = __ffsll((unsigned long long)alive) - 1;
      float bix=__shfl(bx.x,i), biy=__shfl(bx.y,i), biz=__shfl(bx.z,i), biw=__shfl(bx.w,i);
      int gi = __shfl(gj, i);
      if (lane==0){
        atomicOr((unsigned long long*)&gkeep[img*48 + (gi>>6)], 1ull<<(gi&63));
        if (kc < 1024) kbox[kc] = make_float4(bix,biy,biz,biw);
      }
      kc++;
      float ai=(biz-bix)*(biw-biy);
      float ltx=fmaxf(bix,bx.x), lty=fmaxf(biy,bx.y);
      float rbx=fminf(biz,bx.z), rby=fminf(biw,bx.w);
      float wx=fmaxf(rbx-ltx,0.f), wy=fmaxf(rby-lty,0.f);
      float inter=wx*wy;
      float denom=ai+ax; denom=denom-inter; denom=denom+1e-9f;
      bool supp = alive_l && (inter/denom > 0.6f);
      u64 killm = __ballot(supp);
      alive &= ~killm;
      alive &= ~(1ull<<i);
      alive_l = alive_l && !supp;
    }
    __syncthreads();
  }
}

// ---------------- K6: fused emit — one block per (row,img) ----------------
__global__ __launch_bounds__(128)
void emit_kernel(Ptrs p, const float* merged_all, const u64* gkeep, float* out){
  const int r = (int)blockIdx.x, img = (int)blockIdx.y;
  const int tid = (int)threadIdx.x;
  __shared__ int s_i, s_kept;
  if (tid < 64){
    u64 word = (tid < 48) ? gkeep[img*48 + tid] : 0ull;
    int c = (int)__popcll(word);
    int inc = c;
    #pragma unroll
    for (int d=1; d<64; d<<=1){
      int y = __shfl_up(inc, d);
      if (tid >= d) inc += y;
    }
    int excl = inc - c;
    int total = __shfl(inc, 63);
    int kept = total < POST_K ? total : POST_K;
    if (tid==0){ s_kept = kept; s_i = -1; }
    bool sel = (tid<48) && (r < kept) && (excl <= r) && (r < excl + c);
    if (sel){
      u64 w = word; int need = r - excl;
      for (int q=0;q<need;++q) w &= w-1ull;
      s_i = (tid<<6) + (int)__ffsll((unsigned long long)w) - 1;
    }
  }
  __syncthreads();
  const int i = s_i; const int kept = s_kept;
  const bool has = (r < kept) && (i >= 0);
  const float* rec = merged_all + (size_t)img*3072*8 + (size_t)(has?i:0)*8;
  float* obx = out;
  float* osc = out + 3200;
  float* ocl = out + 4000;
  float* ocf = out + 4800;
  float* okv = out + 107200;
  if (tid==0) osc[img*POST_K+r] = has ? sqrtf(fmaxf(rec[4], 1e-12f)) : 0.f;
  if (tid==1) ocl[img*POST_K+r] = has ? rec[5] : -1.0f;
  if (tid==2) okv[img*POST_K+r] = has ? 1.0f : 0.f;
  if (tid>=4 && tid<8) obx[(img*POST_K+r)*4 + (tid-4)] = has ? rec[tid-4] : 0.f;
  float v = 0.f;
  if (has){
    int l = (int)rec[6]; int loc = (int)rec[7];
    int HW = HWof(l);
    v = p.cofs[l][((size_t)img*128 + tid)*HW + loc];
  }
  ocf[(img*POST_K + r)*128 + tid] = v;
}

// ---------------- host ----------------
extern "C" void kernel_launch(void* const* d_in, const int* in_sizes, int n_in,
                              void* d_out, int out_size, void* d_ws, size_t ws_size,
                              hipStream_t stream){
  Ptrs p;
  for (int l=0; l<3; ++l){
    p.locs[l]   = (const float*)d_in[5*l+0];
    p.logits[l] = (const float*)d_in[5*l+1];
    p.reg[l]    = (const float*)d_in[5*l+2];
    p.ctr[l]    = (const float*)d_in[5*l+3];
    p.cofs[l]   = (const float*)d_in[5*l+4];
  }
  char* ws = (char*)d_ws;
  u32* hist1  = (u32*)(ws + OFF_HIST1);
  u32* pcnt   = (u32*)(ws + OFF_PCNT);
  u32* thr    = (u32*)(ws + OFF_THR);
  u32* mcnt   = (u32*)(ws + OFF_MCNT);
  u64* gkeep  = (u64*)(ws + OFF_KEEP);
  u64* pool   = (u64*)(ws + OFF_POOL);
  u64* sorted = (u64*)(ws + OFF_SORT);
  float* clsarr = (float*)(ws + OFF_CLS);
  float* merged = (float*)(ws + OFF_MERG);

  hipMemsetAsync(ws, 0, ZERO_BYTES, stream);
  fused_pass<<<dim3(NBALL,8), 256, 0, stream>>>(p, pcnt, pool, hist1);
  select_kernel<<<24, 256, 0, stream>>>(hist1, pcnt, thr, pool);
  refill_pass<<<dim3(NBALL,8), 256, 0, stream>>>(p, pcnt, thr, pool);   // no-op when ok
  sort_pool<<<24, 1024, 0, stream>>>(thr, pcnt, pool, sorted);
  merge_kernel<<<8, 1024, 0, stream>>>(p, thr, sorted, merged, clsarr, mcnt);
  nms_class<<<dim3(NCLS,8), 64, 0, stream>>>(merged, clsarr, mcnt, gkeep);
  emit_kernel<<<dim3(POST_K,8), 128, 0, stream>>>(p, merged, gkeep, (float*)d_out);
}

// Round 12
// 163.235 us; speedup vs baseline: 1.3953x; 1.0542x over previous
//
#include <hip/hip_runtime.h>

typedef unsigned int u32;
typedef unsigned long long u64;

// ---------------- problem constants ----------------
#define NCLS 80
#define NIMG 8
#define PRE_K 1000
#define POST_K 100
#define PBUF_N 2048

__device__ __forceinline__ int HWof(int l){ return l==0?15200:(l==1?3800:950); }
__device__ __forceinline__ float STRof(int l){ return l==0?8.f:(l==1?16.f:32.f); }
__device__ __forceinline__ u32 CAPof(int l){ return l==0?65536u:32768u; }
__device__ __forceinline__ u32 POFFof(int l){ return l==0?0u:(l==1?65536u:98304u); }

struct Ptrs {
  const float* logits[3];
  const float* reg[3];
  const float* ctr[3];
  const float* cofs[3];
  const float* locs[3];
};

// grid split: 149 lvl0-tiles, 38 lvl1, 10 lvl2 (2048 float4 per tile)
#define NB0 149
#define NB1 38
#define NBALL 197

// ---------------- workspace layout (bytes) ----------------
// zeroed every launch (3392 B only):
#define OFF_PCNT  0u            // 24*4 (pad 128)
#define OFF_CAND  128u          // 24*4 (pad 128)
#define OFF_MCNT  256u          // 32 (pad 64)
#define OFF_KEEP  320u          // 8*48*8 = 3072
#define ZERO_BYTES 3392u
// not zeroed:
#define OFF_THR   3392u         // 24*8*4 = 768 (written before read)
#define OFF_POOL  4224u         // 8*131072*8 = 8388608
#define OFF_SORT  8392832u      // 24*1024*8 = 196608
#define OFF_CLS   8589440u      // 8*3072*4 = 98304
#define OFF_MERG  8687744u      // 8*3072*8*4 = 786432   (total ~9.47 MB)

__device__ __forceinline__ float sigmoidf(float x){ return 1.0f/(1.0f+expf(-x)); }

// ---------------- K1: single full-data pass (candidate count + pool) --------
// Scores: sigmoid(logit) * sigmoid(ctr), inline (validated bit-identical).
// No histogram: per-thread candidate counter (1 LDS atomic/thread) + pool push
// for coarse bin >= static floor {501,500,496} (score >= {0.3125,0.25,0.125}).
template<int LVL>
__device__ __forceinline__ void collect_body(int tile, int img, const Ptrs& p,
                                             u32* cand, u32* pcnt, u64* pool,
                                             u64* pbuf, u32* shctl){
  constexpr int HW   = LVL==0?15200:(LVL==1?3800:950);
  constexpr int NE   = 80*HW;
  constexpr int NF4  = NE/4;
  const u32 CAP = CAPof(LVL);
  const int pair = img*3 + LVL;
  const size_t poff = (size_t)img*131072u + POFFof(LVL);
  const u32 tbin = (LVL==0?501u:(LVL==1?500u:496u));
  const float4* plane = (const float4*)(p.logits[LVL] + (size_t)img*NE);
  const float* cptr = p.ctr[LVL] + (size_t)img*HW;
  if (threadIdx.x==0){ shctl[0]=0; shctl[1]=0; }
  __syncthreads();
  u32 mc = 0;
  #pragma unroll
  for (int k=0;k<8;++k){
    int f4 = tile*2048 + k*256 + (int)threadIdx.x;
    if (f4 < NF4){
      float4 v = plane[f4];
      int e0 = f4*4;
      int cls0 = e0 / HW;
      int loc0 = e0 - cls0*HW;
      float ss[4];
      if (LVL==2){                        // HW=950 not %4: rows can split a float4
        #pragma unroll
        for (int j=0;j<4;++j){ int e=e0+j; int c=e/HW; ss[j]=sigmoidf(cptr[e-c*HW]); }
      } else {                            // HW%4==0: aligned float4 ctr load
        float4 c4 = *(const float4*)(cptr + loc0);
        ss[0]=sigmoidf(c4.x); ss[1]=sigmoidf(c4.y); ss[2]=sigmoidf(c4.z); ss[3]=sigmoidf(c4.w);
      }
      float vv[4] = {v.x,v.y,v.z,v.w};
      #pragma unroll
      for (int j=0;j<4;++j){
        float sl = sigmoidf(vv[j]);
        if (sl > 0.05f){
          mc++;
          u32 bits = __float_as_uint(sl * ss[j]);
          if ((bits>>21) >= tbin){
            int e = e0 + j, cls, loc;
            if (LVL==2){ cls=e/HW; loc=e-cls*HW; } else { cls=cls0; loc=loc0+j; }
            u64 key = ((u64)bits<<32) | (u64)(0xFFFFFFFFu - (u32)(loc*NCLS + cls));
            u32 id = atomicAdd(&shctl[0], 1u);
            if (id < (u32)PBUF_N) pbuf[id] = key;
            else { u32 g = atomicAdd(&pcnt[pair],1u); if (g<CAP) pool[poff+g]=key; }
          }
        }
      }
    }
  }
  if (mc) atomicAdd(&shctl[1], mc);
  __syncthreads();
  u32 m = shctl[0]; if (m > (u32)PBUF_N) m = PBUF_N;
  if (threadIdx.x==0){
    if (m) shctl[2] = atomicAdd(&pcnt[pair], m);
    if (shctl[1]) atomicAdd(&cand[pair], shctl[1]);
  }
  __syncthreads();
  for (u32 i=threadIdx.x; i<m; i+=256){
    u32 d = shctl[2] + i;
    if (d < CAP) pool[poff+d] = pbuf[i];
  }
}

__global__ __launch_bounds__(256)
void fused_pass(Ptrs p, u32* cand, u32* pcnt, u64* pool){
  __shared__ u64 pbuf[PBUF_N];
  __shared__ u32 shctl[4];
  const int bx=(int)blockIdx.x, img=(int)blockIdx.y;
  if (bx<NB0)          collect_body<0>(bx,        img,p,cand,pcnt,pool,pbuf,shctl);
  else if (bx<NB0+NB1) collect_body<1>(bx-NB0,    img,p,cand,pcnt,pool,pbuf,shctl);
  else                 collect_body<2>(bx-NB0-NB1,img,p,cand,pcnt,pool,pbuf,shctl);
}

// ---------------- slow-path helpers (only when pool insufficient) -----------
template<int LVL>
__device__ __forceinline__ void slow_hist(const Ptrs& p, int img, u32* h){
  constexpr int HW = LVL==0?15200:(LVL==1?3800:950);
  constexpr int NE = 80*HW, NF4 = NE/4;
  const float4* plane = (const float4*)(p.logits[LVL] + (size_t)img*NE);
  const float* cptr = p.ctr[LVL] + (size_t)img*HW;
  for (int f4=(int)threadIdx.x; f4<NF4; f4+=1024){
    float4 v = plane[f4];
    int e0=f4*4;
    float vv[4]={v.x,v.y,v.z,v.w};
    #pragma unroll
    for (int j=0;j<4;++j){
      float sl=sigmoidf(vv[j]);
      if (sl>0.05f){
        int e=e0+j; int c=e/HW; int loc=e-c*HW;
        u32 bits=__float_as_uint(sl*sigmoidf(cptr[loc]));
        atomicAdd(&h[bits>>21],1u);
      }
    }
  }
}
template<int LVL>
__device__ __forceinline__ void slow_refill(const Ptrs& p, int img, u32 B1,
                                            u64* pool, size_t poff, u32* cnt){
  constexpr int HW = LVL==0?15200:(LVL==1?3800:950);
  constexpr int NE = 80*HW, NF4 = NE/4;
  const u32 CAP = CAPof(LVL);
  const float4* plane = (const float4*)(p.logits[LVL] + (size_t)img*NE);
  const float* cptr = p.ctr[LVL] + (size_t)img*HW;
  for (int f4=(int)threadIdx.x; f4<NF4; f4+=1024){
    float4 v = plane[f4];
    int e0=f4*4;
    float vv[4]={v.x,v.y,v.z,v.w};
    #pragma unroll
    for (int j=0;j<4;++j){
      float sl=sigmoidf(vv[j]);
      if (sl>0.05f){
        int e=e0+j; int c=e/HW; int loc=e-c*HW;
        u32 bits=__float_as_uint(sl*sigmoidf(cptr[loc]));
        if ((bits>>21) >= B1){
          u32 id = atomicAdd(cnt,1u);
          if (id<CAP) pool[poff+id] = ((u64)bits<<32) |
                        (u64)(0xFFFFFFFFu - (u32)(loc*NCLS + c));
        }
      }
    }
  }
}

// ---------------- K2: fused select + sort (24 independent per-pair blocks) ---
// ok path: pool is provably the exact candidate set with bin >= floor
// (pc<=CAP: no drops; pc>=kk: boundary lies at bin>=floor) -> coarse hist,
// B1, fine hist, T22 all from pool. !ok: in-block full-plane rescan (exact).
__global__ __launch_bounds__(1024)
void selsort(Ptrs p, const u32* cand, const u32* pcnt, u32* thr,
             u64* pool, u64* sorted){
  const int pair=(int)blockIdx.x, lvl=pair%3, img=pair/3;
  const int tid=(int)threadIdx.x;
  __shared__ u64 a[2048];
  __shared__ u32 h[512];
  __shared__ u32 h2[2048];
  __shared__ u32 seg[256], exc[256];
  __shared__ u32 sB1, sCnt, sT22, sgc, scnt;
  const size_t poff = (size_t)img*131072u + POFFof(lvl);
  const u32 CAP = CAPof(lvl);
  const u32 kk = min(cand[pair], (u32)PRE_K);
  if (kk==0){ if (tid==0) thr[pair*8+3]=0u; return; }
  const u32 pcRaw = pcnt[pair];
  const bool ok = (pcRaw <= CAP) && (pcRaw >= kk);
  u32 pc = min(pcRaw, CAP);

  // ---- coarse 512-bin hist ----
  for (int b=tid;b<512;b+=1024) h[b]=0;
  __syncthreads();
  if (ok){
    for (u32 i=tid;i<pc;i+=1024) atomicAdd(&h[(u32)(pool[poff+i]>>53)],1u);
  } else {
    if (lvl==0)      slow_hist<0>(p,img,h);
    else if (lvl==1) slow_hist<1>(p,img,h);
    else             slow_hist<2>(p,img,h);
  }
  __syncthreads();
  if (tid<256) seg[tid] = h[511-2*tid] + h[511-(2*tid+1)];
  __syncthreads();
  if (tid==0){ u32 run=0; for(int i=0;i<256;++i){ exc[i]=run; run+=seg[i]; } }
  __syncthreads();
  if (tid<256){
    u32 cum=exc[tid];
    #pragma unroll
    for (int q=0;q<2;++q){
      int bin=511-(2*tid+q); u32 c=h[bin];
      if (c && cum<kk && cum+c>=kk){ sB1=(u32)bin; sCnt=cum; }
      cum+=c;
    }
  }
  __syncthreads();
  const u32 B1=sB1, cntAb=sCnt;
  if (!ok){
    if (tid==0) sgc=0;
    __syncthreads();
    if (lvl==0)      slow_refill<0>(p,img,B1,pool,poff,&sgc);
    else if (lvl==1) slow_refill<1>(p,img,B1,pool,poff,&sgc);
    else             slow_refill<2>(p,img,B1,pool,poff,&sgc);
    __syncthreads();
    pc = min(sgc, CAP);
  }
  // ---- fine 2048-bin hist within bin B1 ----
  for (int b=tid;b<2048;b+=1024) h2[b]=0;
  __syncthreads();
  for (u32 i=tid;i<pc;i+=1024){
    u64 key=pool[poff+i];
    if ((u32)(key>>53)==B1) atomicAdd(&h2[(u32)(key>>42)&0x7FFu],1u);
  }
  __syncthreads();
  const u32 KK2 = kk - cntAb;
  if (tid<256){
    u32 part=0;
    #pragma unroll
    for (int q=0;q<8;++q) part += h2[2047-(tid*8+q)];
    seg[tid]=part;
  }
  __syncthreads();
  if (tid==0){ u32 run=0; for(int i=0;i<256;++i){ exc[i]=run; run+=seg[i]; } }
  __syncthreads();
  if (tid<256){
    u32 cum=exc[tid];
    #pragma unroll
    for (int q=0;q<8;++q){
      int bin=2047-(tid*8+q); u32 c=h2[bin];
      if (c && cum<KK2 && cum+c>=KK2) sT22=(B1<<11)|(u32)bin;
      cum+=c;
    }
  }
  __syncthreads();
  const u32 T22=sT22;
  // ---- gather keys >= T22, bitonic 2048 descending, emit top-kk ----
  for (int i=tid;i<2048;i+=1024) a[i]=0ull;
  if (tid==0) scnt=0;
  __syncthreads();
  for (u32 i=tid;i<pc;i+=1024){
    u64 k = pool[poff+i];
    if ((u32)(k>>42) >= T22){
      u32 id = atomicAdd(&scnt,1u);
      if (id < 2048u) a[id]=k;
    }
  }
  __syncthreads();
  const u32 n = min(scnt, 2048u);
  for (int k=2;k<=2048;k<<=1){
    for (int j=k>>1;j>0;j>>=1){
      for (int t=tid;t<2048;t+=1024){
        int ix = t ^ j;
        if (ix > t){
          u64 x=a[t], y=a[ix];
          bool up = ((t & k)==0);
          if (up ? (x<y) : (x>y)){ a[t]=y; a[ix]=x; }
        }
      }
      __syncthreads();
    }
  }
  u32 m = kk < n ? kk : n;
  for (u32 r=tid;r<m;r+=1024) sorted[(size_t)pair*1024+r]=a[r];
  if (tid==0) thr[pair*8+3]=m;
}

// ---------------- K3: 3-way stable merge + box decode (+ class array) --------
__global__ void merge_kernel(Ptrs p, const u32* thr, const u64* sorted,
                             float* merged, float* clsarr, u32* mcnt){
#pragma clang fp contract(off)
  const int img = blockIdx.x;
  __shared__ u64 mk[3][1024];
  __shared__ int n[3];
  if (threadIdx.x < 3) n[threadIdx.x] = (int)thr[(img*3+threadIdx.x)*8+3];
  __syncthreads();
  const int n0=n[0], n1=n[1], n2=n[2];
  for (int idx=threadIdx.x; idx<3*1024; idx+=blockDim.x){
    int l = idx>>10, r = idx&1023;
    if (r < n[l]){
      u64 key = sorted[(size_t)(img*3+l)*1024 + r];
      mk[l][r] = (key & 0xFFFFFFFF00000000ull) |
                 (u64)(0xFFFFFFFFu - (u32)(l*PRE_K + r));  // concat-idx tie-break
    }
  }
  __syncthreads();
  const int T = n0+n1+n2;
  if (threadIdx.x==0) mcnt[img] = (u32)T;
  for (int t=threadIdx.x; t<T; t+=blockDim.x){
    int l, r;
    if (t < n0){ l=0; r=t; }
    else if (t < n0+n1){ l=1; r=t-n0; }
    else { l=2; r=t-n0-n1; }
    u64 x = mk[l][r];
    int pos = r;
    #pragma unroll
    for (int o=0;o<3;++o) if (o!=l){
      int lo=0, hi=n[o];
      while (lo<hi){ int m=(lo+hi)>>1; if (mk[o][m] > x) lo=m+1; else hi=m; }
      pos += lo;
    }
    u64 key = sorted[(size_t)(img*3+l)*1024 + r];
    u32 flat = 0xFFFFFFFFu - (u32)(key & 0xFFFFFFFFull);
    float score = __uint_as_float((u32)(key>>32));
    int HW = HWof(l);
    int loc = (int)(flat / (u32)NCLS);
    int cls = (int)(flat - (u32)loc*NCLS);
    float lx = p.locs[l][2*loc], ly = p.locs[l][2*loc+1];
    float st = STRof(l);
    const float* rg = p.reg[l] + (size_t)img*4*HW + loc;
    float r0 = rg[0]*st, r1 = rg[HW]*st, r2 = rg[2*(size_t)HW]*st, r3 = rg[3*(size_t)HW]*st;
    float x1 = fminf(fmaxf(lx - r0, 0.f), 1216.f);
    float y1 = fminf(fmaxf(ly - r1, 0.f),  800.f);
    float x2 = fminf(fmaxf(lx + r2, 0.f), 1216.f);
    float y2 = fminf(fmaxf(ly + r3, 0.f),  800.f);
    float* out = merged + (size_t)(img*3072 + pos)*8;
    out[0]=x1; out[1]=y1; out[2]=x2; out[3]=y2;
    out[4]=score; out[5]=(float)cls; out[6]=(float)l; out[7]=(float)loc;
    clsarr[img*3072 + pos] = (float)cls;
  }
}

// ---------------- K4: per-class greedy NMS (640 independent tasks) ----------
__global__ __launch_bounds__(64)
void nms_class(const float* merged_all, const float* clsarr, const u32* mcnt, u64* gkeep){
#pragma clang fp contract(off)
  const int c = (int)blockIdx.x, img = (int)blockIdx.y;
  const float* merged = merged_all + (size_t)img*3072*8;
  const float* carr = clsarr + (size_t)img*3072;
  const int T = (int)mcnt[img];
  const int lane = (int)threadIdx.x;
  __shared__ unsigned short mlist[3072];
  __shared__ float4 kbox[1024];

  float fv[48];
  #pragma unroll
  for (int w=0; w<48; ++w){
    int j = w*64 + lane;
    fv[w] = (j < T) ? carr[j] : -1.0f;
  }
  int base = 0;
  const u64 lanemask = (lane==0) ? 0ull : ((~0ull) >> (64-lane));
  #pragma unroll
  for (int w=0; w<48; ++w){
    bool mem = ((int)fv[w] == c);
    u64 word = __ballot(mem);
    if (mem){
      int rank = base + (int)__popcll(word & lanemask);
      mlist[rank] = (unsigned short)(w*64 + lane);
    }
    base += (int)__popcll(word);
  }
  const int n = base;
  if (n == 0) return;
  __syncthreads();

  const float off = (float)c * 1217.0f;
  int kc = 0;
  for (int t0 = 0; t0 < n; t0 += 64){
    int r = t0 + lane;
    bool valid = (r < n);
    float4 bx = make_float4(0.f,0.f,0.f,0.f);
    int gj = 0;
    if (valid){
      gj = (int)mlist[r];
      const float* rec = merged + (size_t)gj*8;
      bx = make_float4(rec[0]+off, rec[1]+off, rec[2]+off, rec[3]+off);
    }
    float ax = (bx.z-bx.x)*(bx.w-bx.y);
    bool alive_l = valid;
    for (int q=0; q<kc; ++q){
      float4 bq = kbox[q];
      float aq = (bq.z-bq.x)*(bq.w-bq.y);
      float ltx=fmaxf(bq.x,bx.x), lty=fmaxf(bq.y,bx.y);
      float rbx=fminf(bq.z,bx.z), rby=fminf(bq.w,bx.w);
      float wx=fmaxf(rbx-ltx,0.f), wy=fmaxf(rby-lty,0.f);
      float inter=wx*wy;
      float denom=aq+ax; denom=denom-inter; denom=denom+1e-9f;
      if (alive_l && (inter/denom > 0.6f)) alive_l=false;
    }
    u64 alive = __ballot(alive_l);
    while (alive){
      int i = __ffsll((unsigned long long)alive) - 1;
      float bix=__shfl(bx.x,i), biy=__shfl(bx.y,i), biz=__shfl(bx.z,i), biw=__shfl(bx.w,i);
      int gi = __shfl(gj, i);
      if (lane==0){
        atomicOr((unsigned long long*)&gkeep[img*48 + (gi>>6)], 1ull<<(gi&63));
        if (kc < 1024) kbox[kc] = make_float4(bix,biy,biz,biw);
      }
      kc++;
      float ai=(biz-bix)*(biw-biy);
      float ltx=fmaxf(bix,bx.x), lty=fmaxf(biy,bx.y);
      float rbx=fminf(biz,bx.z), rby=fminf(biw,bx.w);
      float wx=fmaxf(rbx-ltx,0.f), wy=fmaxf(rby-lty,0.f);
      float inter=wx*wy;
      float denom=ai+ax; denom=denom-inter; denom=denom+1e-9f;
      bool supp = alive_l && (inter/denom > 0.6f);
      u64 killm = __ballot(supp);
      alive &= ~killm;
      alive &= ~(1ull<<i);
      alive_l = alive_l && !supp;
    }
    __syncthreads();
  }
}

// ---------------- K5: fused emit — one block per (row,img) ----------------
__global__ __launch_bounds__(128)
void emit_kernel(Ptrs p, const float* merged_all, const u64* gkeep, float* out){
  const int r = (int)blockIdx.x, img = (int)blockIdx.y;
  const int tid = (int)threadIdx.x;
  __shared__ int s_i, s_kept;
  if (tid < 64){
    u64 word = (tid < 48) ? gkeep[img*48 + tid] : 0ull;
    int c = (int)__popcll(word);
    int inc = c;
    #pragma unroll
    for (int d=1; d<64; d<<=1){
      int y = __shfl_up(inc, d);
      if (tid >= d) inc += y;
    }
    int excl = inc - c;
    int total = __shfl(inc, 63);
    int kept = total < POST_K ? total : POST_K;
    if (tid==0){ s_kept = kept; s_i = -1; }
    bool sel = (tid<48) && (r < kept) && (excl <= r) && (r < excl + c);
    if (sel){
      u64 w = word; int need = r - excl;
      for (int q=0;q<need;++q) w &= w-1ull;
      s_i = (tid<<6) + (int)__ffsll((unsigned long long)w) - 1;
    }
  }
  __syncthreads();
  const int i = s_i; const int kept = s_kept;
  const bool has = (r < kept) && (i >= 0);
  const float* rec = merged_all + (size_t)img*3072*8 + (size_t)(has?i:0)*8;
  float* obx = out;
  float* osc = out + 3200;
  float* ocl = out + 4000;
  float* ocf = out + 4800;
  float* okv = out + 107200;
  if (tid==0) osc[img*POST_K+r] = has ? sqrtf(fmaxf(rec[4], 1e-12f)) : 0.f;
  if (tid==1) ocl[img*POST_K+r] = has ? rec[5] : -1.0f;
  if (tid==2) okv[img*POST_K+r] = has ? 1.0f : 0.f;
  if (tid>=4 && tid<8) obx[(img*POST_K+r)*4 + (tid-4)] = has ? rec[tid-4] : 0.f;
  float v = 0.f;
  if (has){
    int l = (int)rec[6]; int loc = (int)rec[7];
    int HW = HWof(l);
    v = p.cofs[l][((size_t)img*128 + tid)*HW + loc];
  }
  ocf[(img*POST_K + r)*128 + tid] = v;
}

// ---------------- host ----------------
extern "C" void kernel_launch(void* const* d_in, const int* in_sizes, int n_in,
                              void* d_out, int out_size, void* d_ws, size_t ws_size,
                              hipStream_t stream){
  Ptrs p;
  for (int l=0; l<3; ++l){
    p.locs[l]   = (const float*)d_in[5*l+0];
    p.logits[l] = (const float*)d_in[5*l+1];
    p.reg[l]    = (const float*)d_in[5*l+2];
    p.ctr[l]    = (const float*)d_in[5*l+3];
    p.cofs[l]   = (const float*)d_in[5*l+4];
  }
  char* ws = (char*)d_ws;
  u32* pcnt   = (u32*)(ws + OFF_PCNT);
  u32* cand   = (u32*)(ws + OFF_CAND);
  u32* mcnt   = (u32*)(ws + OFF_MCNT);
  u64* gkeep  = (u64*)(ws + OFF_KEEP);
  u32* thr    = (u32*)(ws + OFF_THR);
  u64* pool   = (u64*)(ws + OFF_POOL);
  u64* sorted = (u64*)(ws + OFF_SORT);
  float* clsarr = (float*)(ws + OFF_CLS);
  float* merged = (float*)(ws + OFF_MERG);

  hipMemsetAsync(ws, 0, ZERO_BYTES, stream);
  fused_pass<<<dim3(NBALL,8), 256, 0, stream>>>(p, cand, pcnt, pool);
  selsort<<<24, 1024, 0, stream>>>(p, cand, pcnt, thr, pool, sorted);
  merge_kernel<<<8, 1024, 0, stream>>>(p, thr, sorted, merged, clsarr, mcnt);
  nms_class<<<dim3(NCLS,8), 64, 0, stream>>>(merged, clsarr, mcnt, gkeep);
  emit_kernel<<<dim3(POST_K,8), 128, 0, stream>>>(p, merged, gkeep, (float*)d_out);
}